// Round 5
// baseline (5643.900 us; speedup 1.0000x reference)
//
#include <hip/hip_runtime.h>
#include <cstdint>
#include <cstddef>

#define S_LEN 256
#define BATCH 64
#define HID   1024
#define GATES 4096
#define NBLK  128
#define FLAG_STRIDE 32   // 32 uints = 128 B: one cache line per block's flag

typedef _Float16 h16;
typedef _Float16 h16x8 __attribute__((ext_vector_type(8)));
typedef _Float16 h16x4 __attribute__((ext_vector_type(4)));
typedef float    f32x4 __attribute__((ext_vector_type(4)));

// ---------------------------------------------------------------------------
// x fp32 -> fp16 (one pass)
// ---------------------------------------------------------------------------
__global__ __launch_bounds__(256)
void xconv_kernel(const float* __restrict__ x, h16* __restrict__ x16)
{
  const int n4 = S_LEN * BATCH * HID / 4;
  const int stride = gridDim.x * 256;
  for (int i = blockIdx.x * 256 + threadIdx.x; i < n4; i += stride) {
    f32x4 v = ((const f32x4*)x)[i];
    h16x4 o;
    o[0] = (h16)v[0]; o[1] = (h16)v[1]; o[2] = (h16)v[2]; o[3] = (h16)v[3];
    ((h16x4*)x16)[i] = o;
  }
}

// ---------------------------------------------------------------------------
// Flat one-hop grid barrier: every block release-stores its own padded flag;
// every block's first NBLK threads each poll ONE flag directly (no block-0
// relay). One acquire load invalidates L1/L2 before the next step's reads.
// Monotone counters; flags zeroed per kernel_launch.
// ---------------------------------------------------------------------------
__device__ __forceinline__ void grid_barrier(unsigned* flags, int g, int wg)
{
  __syncthreads();                      // drains vmcnt: block's h-stores issued
  const unsigned tgt = (unsigned)(g + 1);
  if (threadIdx.x == 0)
    __hip_atomic_store(&flags[wg * FLAG_STRIDE], tgt,
                       __ATOMIC_RELEASE, __HIP_MEMORY_SCOPE_AGENT);
  if (threadIdx.x < NBLK) {
    while (__hip_atomic_load(&flags[threadIdx.x * FLAG_STRIDE],
                             __ATOMIC_RELAXED, __HIP_MEMORY_SCOPE_AGENT) < tgt) {}
  }
  if (threadIdx.x == 0)
    (void)__hip_atomic_load(&flags[0], __ATOMIC_ACQUIRE, __HIP_MEMORY_SCOPE_AGENT);
  __syncthreads();
}

// ---------------------------------------------------------------------------
// Persistent 2-layer pipelined LSTM. 128 WGs x 256 thr.
// WG wg: layer = wg>>6, owns h-cols j0..j0+15 => 64 gate-cols as 4 n-tiles
// (one per gate g: cols g*1024 + j0 + 0..15).
// Weights (K=2048 = [W_ih | W_hh]) live ENTIRELY in VGPRs: per wave
// breg[4 gate][16 kslice] h16x8 = 256 VGPRs, loaded once fp32->fp16.
// Step g: layer0 computes t=g (g<256), layer1 computes t=g-1 (g>=1).
// Wave w: K-slice [w*512,(w+1)*512): waves 0-1 input matrix, 2-3 h_prev.
// Cross-wave K-reduce via 16KB XOR-swizzled LDS, 4 m-rounds, gates+c+h fused.
// ---------------------------------------------------------------------------
__global__ __launch_bounds__(256, 1)
void lstm_persistent(const h16* __restrict__ x16,
                     const float* __restrict__ weight,
                     const float* __restrict__ bias,
                     h16* __restrict__ h0r,
                     h16* __restrict__ h1r,
                     unsigned* __restrict__ flags)
{
  __shared__ float plds[4][16][64];   // 16 KB

  const int wg    = blockIdx.x;
  const int layer = wg >> 6;
  const int j0    = (wg & 63) * 16;
  const int tid   = threadIdx.x;
  const int wave  = tid >> 6, lane = tid & 63;
  const int l15   = lane & 15, l16 = lane >> 4;

  // ---- one-time: load this wave's B-fragments fp32 -> fp16 registers ----
  h16x8 breg[4][16];
  {
    const float* wih = weight + (size_t)layer * 2 * GATES * HID;
    const float* wbase = (wave < 2) ? wih : wih + (size_t)GATES * HID;
    const int kh = (wave & 1) * 512 + l16 * 8;
#pragma unroll
    for (int gg = 0; gg < 4; ++gg) {
      const float* colp = wbase + (size_t)(gg * HID + j0 + l15) * HID + kh;
#pragma unroll
      for (int s = 0; s < 16; ++s) {
        const float* p = colp + s * 32;
        h16x8 v;
#pragma unroll
        for (int e = 0; e < 8; ++e) v[e] = (h16)p[e];
        breg[gg][s] = v;
      }
    }
  }
  // combined bias for this thread's jj (same across m-rounds)
  float bc[4];
  {
    const int jj = tid & 15;
#pragma unroll
    for (int gg = 0; gg < 4; ++gg) {
      const int col = gg * HID + j0 + jj;
      bc[gg] = bias[(size_t)layer * 2 * GATES + col] +
               bias[(size_t)layer * 2 * GATES + GATES + col];
    }
  }
  float creg[4] = {0.f, 0.f, 0.f, 0.f};

  for (int g = 0; g <= S_LEN; ++g) {
    const bool active = (layer == 0) ? (g < S_LEN) : (g >= 1);
    if (active) {
      const h16 *Alo, *Ahi;
      h16* Hout;
      if (layer == 0) {
        Alo  = x16 + (size_t)g * (BATCH * HID);
        Ahi  = h0r + (size_t)((g + 1) & 1) * (BATCH * HID);
        Hout = h0r + (size_t)(g & 1) * (BATCH * HID);
      } else {
        Alo  = h0r + (size_t)((g - 1) & 1) * (BATCH * HID);
        Ahi  = h1r + (size_t)(g & 1) * (BATCH * HID);
        Hout = h1r + (size_t)((g - 1) & 1) * (BATCH * HID);
      }
      const h16* Asrc = (wave < 2) ? Alo : Ahi;
      const int kbase = (wave & 1) * 512;

      const h16* arow[4];
#pragma unroll
      for (int i = 0; i < 4; ++i)
        arow[i] = Asrc + (size_t)(i * 16 + l15) * HID + kbase + l16 * 8;

      f32x4 acc[4][4];   // [m-tile i][gate gg]
#pragma unroll
      for (int i = 0; i < 4; ++i)
#pragma unroll
        for (int gg = 0; gg < 4; ++gg) acc[i][gg] = (f32x4)0.f;

#pragma unroll
      for (int s = 0; s < 16; ++s) {
        h16x8 a[4];
#pragma unroll
        for (int i = 0; i < 4; ++i) a[i] = *(const h16x8*)(arow[i] + s * 32);
#pragma unroll
        for (int i = 0; i < 4; ++i)
#pragma unroll
          for (int gg = 0; gg < 4; ++gg)
            acc[i][gg] = __builtin_amdgcn_mfma_f32_16x16x32_f16(a[i], breg[gg][s],
                                                                acc[i][gg], 0, 0, 0);
      }

      // ---- cross-wave reduce + activations, 4 m-rounds of 16 rows ----
#pragma unroll
      for (int i = 0; i < 4; ++i) {
#pragma unroll
        for (int gg = 0; gg < 4; ++gg)
#pragma unroll
          for (int q = 0; q < 4; ++q) {
            const int row = l16 * 4 + q;                       // 0..15
            const int colS = (gg * 16 + l15) ^ ((row & 7) << 2);
            plds[wave][row][colS] = acc[i][gg][q];
          }
        __syncthreads();
        {
          const int row = tid >> 4, jj = tid & 15;
          float gv[4];
#pragma unroll
          for (int gg = 0; gg < 4; ++gg) {
            const int colS = (gg * 16 + jj) ^ ((row & 7) << 2);
            float s = bc[gg];
#pragma unroll
            for (int w = 0; w < 4; ++w) s += plds[w][row][colS];
            gv[gg] = s;
          }
          const float ig = 1.f / (1.f + __expf(-gv[0]));
          const float fg = 1.f / (1.f + __expf(-gv[1]));
          const float gt = 1.f - 2.f / (__expf(2.f * gv[2]) + 1.f);
          const float og = 1.f / (1.f + __expf(-gv[3]));
          const float cn = fg * creg[i] + ig * gt;
          creg[i] = cn;
          const float th = 1.f - 2.f / (__expf(2.f * cn) + 1.f);
          Hout[(size_t)(i * 16 + row) * HID + j0 + jj] = (h16)(og * th);
        }
        __syncthreads();
      }
    }
    grid_barrier(flags, g, wg);
  }
}

// ---------------------------------------------------------------------------
// out[m][cls] = h[m] . fc_w[cls] + fc_b[cls]. One wave per output.
// ---------------------------------------------------------------------------
__global__ __launch_bounds__(256)
void fc_kernel(const h16* __restrict__ h,
               const float* __restrict__ fw,
               const float* __restrict__ fb,
               float* __restrict__ out)
{
  const int gw = (blockIdx.x * blockDim.x + threadIdx.x) >> 6;
  const int lane = threadIdx.x & 63;
  if (gw >= BATCH * 10) return;
  const int m = gw / 10, cls = gw % 10;
  float s = 0.f;
  for (int k = lane; k < HID; k += 64)
    s += (float)h[(size_t)m * HID + k] * fw[(size_t)cls * HID + k];
#pragma unroll
  for (int off = 32; off; off >>= 1) s += __shfl_down(s, off);
  if (lane == 0) out[m * 10 + cls] = s + fb[cls];
}

// ---------------------------------------------------------------------------
extern "C" void kernel_launch(void* const* d_in, const int* in_sizes, int n_in,
                              void* d_out, int out_size, void* d_ws, size_t ws_size,
                              hipStream_t stream)
{
  const float* x      = (const float*)d_in[0];   // [256][64][1024]
  const float* weight = (const float*)d_in[1];   // [2][2][4096][1024]
  const float* bias   = (const float*)d_in[2];   // [2][2][4096]
  const float* fc_w   = (const float*)d_in[3];   // [10][1024]
  const float* fc_b   = (const float*)d_in[4];   // [10]
  float* out = (float*)d_out;                    // [64][10]

  auto align = [](size_t v) { return (v + 255) & ~(size_t)255; };
  const size_t flags_sz = (size_t)NBLK * FLAG_STRIDE * sizeof(unsigned); // 16 KB
  const size_t x16_sz  = (size_t)S_LEN * BATCH * HID * sizeof(h16);      // 32 MB
  const size_t ring_sz = (size_t)2 * BATCH * HID * sizeof(h16);          // 256 KB

  char* p = (char*)d_ws;
  unsigned* flags = (unsigned*)p; p += align(flags_sz);
  h16* x16 = (h16*)p; p += align(x16_sz);
  h16* h0r = (h16*)p; p += align(ring_sz);
  h16* h1r = (h16*)p; p += align(ring_sz);

  hipMemsetAsync(flags, 0, flags_sz, stream);
  hipMemsetAsync(h0r, 0, ring_sz, stream);
  hipMemsetAsync(h1r, 0, ring_sz, stream);

  xconv_kernel<<<dim3(2048), 256, 0, stream>>>(x, x16);

  lstm_persistent<<<dim3(NBLK), dim3(256), 0, stream>>>(
      x16, weight, bias, h0r, h1r, flags);

  // final h of top layer: t = 255 -> ring slot 1
  fc_kernel<<<dim3((BATCH * 10 * 64) / 256), 256, 0, stream>>>(
      h1r + (size_t)BATCH * HID, fc_w, fc_b, out);
}

// Round 6
// 5401.311 us; speedup vs baseline: 1.0449x; 1.0449x over previous
//
#include <hip/hip_runtime.h>
#include <cstdint>
#include <cstddef>

#define S_LEN 256
#define BATCH 64
#define HID   1024
#define GATES 4096
#define NBLK  256
#define FLAG_STRIDE 32   // 32 uints = 128 B: one cache line per block's flag

typedef _Float16 h16;
typedef _Float16 h16x8 __attribute__((ext_vector_type(8)));
typedef _Float16 h16x4 __attribute__((ext_vector_type(4)));
typedef float    f32x4 __attribute__((ext_vector_type(4)));

// ---------------------------------------------------------------------------
// x fp32 -> fp16 (one pass)
// ---------------------------------------------------------------------------
__global__ __launch_bounds__(256)
void xconv_kernel(const float* __restrict__ x, h16* __restrict__ x16)
{
  const int n4 = S_LEN * BATCH * HID / 4;
  const int stride = gridDim.x * 256;
  for (int i = blockIdx.x * 256 + threadIdx.x; i < n4; i += stride) {
    f32x4 v = ((const f32x4*)x)[i];
    h16x4 o;
    o[0] = (h16)v[0]; o[1] = (h16)v[1]; o[2] = (h16)v[2]; o[3] = (h16)v[3];
    ((h16x4*)x16)[i] = o;
  }
}

// ---------------------------------------------------------------------------
// Tree grid barrier, ALL-RELAXED (no acquire/release -> no buffer_wbl2 /
// buffer_inv cache maintenance). Safe because all cross-XCD payload (h ring)
// moves via agent-scope (sc1) loads/stores that are device-visible once
// vmcnt retires, and __syncthreads() drains vmcnt before the flag store.
// ---------------------------------------------------------------------------
__device__ __forceinline__ void grid_barrier(unsigned* flags, unsigned* go,
                                             int g, int wg)
{
  __syncthreads();                      // vmcnt(0): sc1 h-stores device-visible
  const unsigned tgt = (unsigned)(g + 1);
  if (threadIdx.x == 0)
    __hip_atomic_store(&flags[wg * FLAG_STRIDE], tgt,
                       __ATOMIC_RELAXED, __HIP_MEMORY_SCOPE_AGENT);
  if (wg == 0) {
    while (__hip_atomic_load(&flags[threadIdx.x * FLAG_STRIDE],
                             __ATOMIC_RELAXED, __HIP_MEMORY_SCOPE_AGENT) < tgt) {}
    __syncthreads();
    if (threadIdx.x == 0)
      __hip_atomic_store(go, tgt, __ATOMIC_RELAXED, __HIP_MEMORY_SCOPE_AGENT);
  }
  if (threadIdx.x == 0) {
    while (__hip_atomic_load(go, __ATOMIC_RELAXED,
                             __HIP_MEMORY_SCOPE_AGENT) < tgt) {}
  }
  __syncthreads();
}

// ---------------------------------------------------------------------------
// Persistent 2-layer pipelined LSTM. 256 WGs x 256 thr (1 per CU).
// WG wg: layer = wg>>7, owns hidden cols j0..j0+7 (32 gate-cols).
// Weights (K=2048 = [W_ih | W_hh]) packed fp16 in 128KB LDS, loaded once.
// Step g: layer0 computes t=g (g<256), layer1 computes t=g-1 (g>=1).
// Wave w covers K-slice w*512..: waves 0-1 input part, waves 2-3 hidden part.
// h-ring traffic is agent-scope (sc1, L3-coherent); x16 reads are plain
// (L2-cached; nothing invalidates L2 anymore).
// Cross-wave K-reduce via 16KB XOR-swizzled LDS, gates+c+h fused.
// ---------------------------------------------------------------------------
__global__ __launch_bounds__(256, 1)
void lstm_persistent(const h16* __restrict__ x16,
                     const float* __restrict__ weight,
                     const float* __restrict__ bias,
                     h16* __restrict__ h0r,
                     h16* __restrict__ h1r,
                     unsigned* __restrict__ flags,
                     unsigned* __restrict__ go)
{
  __shared__ h16  wlds[65536];   // 128 KB: [2 f][64 ks][64 lane][8]
  __shared__ float plds[4096];   // 16 KB : [4 wave][32 row][32 colS]

  const int wg    = blockIdx.x;
  const int layer = wg >> 7;
  const int j0    = (wg & 127) * 8;
  const int tid   = threadIdx.x;
  const int wave  = tid >> 6, lane = tid & 63;
  const int l15   = lane & 15, l16 = lane >> 4;

  // ---- one-time: pack this WG's weight slice fp32->fp16 into LDS ----
  {
    const float* wsrc = weight + (size_t)layer * 2 * GATES * HID;
    for (int c = tid; c < 8192; c += 256) {           // c = f*4096 + ks*64 + cl
      const int cl = c & 63, ks = (c >> 6) & 63, f = c >> 12;
      const int nl  = f * 16 + (cl & 15);
      const int col = (nl >> 3) * HID + j0 + (nl & 7);
      const int k   = ks * 32 + (cl >> 4) * 8;
      const float* p = wsrc + (k < HID ? (size_t)0 : (size_t)GATES * HID)
                            + (size_t)col * HID + (k & (HID - 1));
      h16x8 v;
#pragma unroll
      for (int e = 0; e < 8; ++e) v[e] = (h16)p[e];
      *(h16x8*)&wlds[(size_t)c * 8] = v;
    }
  }
  // combined bias for this thread's j (same j both m-rounds)
  float bc[4];
  {
    const int j = tid & 7;
#pragma unroll
    for (int gg = 0; gg < 4; ++gg) {
      const int col = gg * HID + j0 + j;
      bc[gg] = bias[(size_t)layer * 2 * GATES + col] +
               bias[(size_t)layer * 2 * GATES + GATES + col];
    }
  }
  float creg[2] = {0.f, 0.f};
  __syncthreads();

  for (int g = 0; g <= S_LEN; ++g) {
    const bool active = (layer == 0) ? (g < S_LEN) : (g >= 1);
    if (active) {
      const h16 *Alo, *Ahi;
      h16* Hout;
      if (layer == 0) {
        Alo  = x16 + (size_t)g * (BATCH * HID);
        Ahi  = h0r + (size_t)((g + 1) & 1) * (BATCH * HID);
        Hout = h0r + (size_t)(g & 1) * (BATCH * HID);
      } else {
        Alo  = h0r + (size_t)((g - 1) & 1) * (BATCH * HID);
        Ahi  = h1r + (size_t)(g & 1) * (BATCH * HID);
        Hout = h1r + (size_t)((g - 1) & 1) * (BATCH * HID);
      }
      const h16* Asrc = (wave < 2) ? Alo : Ahi;
      const bool ring = (layer == 1) || (wave >= 2);   // wave-uniform
      const int kbase = (wave & 1) * 512;

      const h16* arow[4];
#pragma unroll
      for (int i = 0; i < 4; ++i)
        arow[i] = Asrc + (size_t)(i * 16 + l15) * HID + kbase + l16 * 8;
      const h16* bbase = wlds + wave * 8192 + lane * 8;

      f32x4 acc[4][2];
#pragma unroll
      for (int i = 0; i < 4; ++i)
#pragma unroll
        for (int n2 = 0; n2 < 2; ++n2) acc[i][n2] = (f32x4)0.f;

#pragma unroll
      for (int s = 0; s < 16; ++s) {
        const h16x8 b0 = *(const h16x8*)(bbase + s * 512);
        const h16x8 b1 = *(const h16x8*)(bbase + 32768 + s * 512);
#pragma unroll
        for (int i = 0; i < 4; ++i) {
          h16x8 a;
          if (ring) {
            const unsigned long long* p =
                (const unsigned long long*)(arow[i] + s * 32);
            union { unsigned long long u[2]; h16x8 v; } cv;
            cv.u[0] = __hip_atomic_load(p, __ATOMIC_RELAXED,
                                        __HIP_MEMORY_SCOPE_AGENT);
            cv.u[1] = __hip_atomic_load(p + 1, __ATOMIC_RELAXED,
                                        __HIP_MEMORY_SCOPE_AGENT);
            a = cv.v;
          } else {
            a = *(const h16x8*)(arow[i] + s * 32);
          }
          acc[i][0] = __builtin_amdgcn_mfma_f32_16x16x32_f16(a, b0, acc[i][0], 0, 0, 0);
          acc[i][1] = __builtin_amdgcn_mfma_f32_16x16x32_f16(a, b1, acc[i][1], 0, 0, 0);
        }
      }

      // ---- cross-wave reduce + activations, 2 m-rounds of 32 rows ----
#pragma unroll
      for (int r = 0; r < 2; ++r) {
#pragma unroll
        for (int ii = 0; ii < 2; ++ii) {
          const int i = r * 2 + ii;
#pragma unroll
          for (int n2 = 0; n2 < 2; ++n2)
#pragma unroll
            for (int q = 0; q < 4; ++q) {
              const int row = ii * 16 + l16 * 4 + q;            // 0..31
              const int colS = (n2 * 16 + l15) ^ ((row & 7) << 2);
              plds[(wave * 32 + row) * 32 + colS] = acc[i][n2][q];
            }
        }
        __syncthreads();
        {
          const int mr = tid >> 3, j = tid & 7;
          float gv[4];
#pragma unroll
          for (int gg = 0; gg < 4; ++gg) {
            const int colS = (gg * 8 + j) ^ ((mr & 7) << 2);
            float s = bc[gg];
#pragma unroll
            for (int w = 0; w < 4; ++w) s += plds[(w * 32 + mr) * 32 + colS];
            gv[gg] = s;
          }
          const float ig = 1.f / (1.f + __expf(-gv[0]));
          const float fg = 1.f / (1.f + __expf(-gv[1]));
          const float gt = 1.f - 2.f / (__expf(2.f * gv[2]) + 1.f);
          const float og = 1.f / (1.f + __expf(-gv[3]));
          const float cn = fg * creg[r] + ig * gt;
          creg[r] = cn;
          const float th = 1.f - 2.f / (__expf(2.f * cn) + 1.f);
          union { h16 f; unsigned short u; } hb;
          hb.f = (h16)(og * th);
          __hip_atomic_store(
              (unsigned short*)&Hout[(size_t)(r * 32 + mr) * HID + j0 + j],
              hb.u, __ATOMIC_RELAXED, __HIP_MEMORY_SCOPE_AGENT);
        }
        __syncthreads();
      }
    }
    grid_barrier(flags, go, g, wg);
  }
}

// ---------------------------------------------------------------------------
// out[m][cls] = h[m] . fc_w[cls] + fc_b[cls]. One wave per output.
// ---------------------------------------------------------------------------
__global__ __launch_bounds__(256)
void fc_kernel(const h16* __restrict__ h,
               const float* __restrict__ fw,
               const float* __restrict__ fb,
               float* __restrict__ out)
{
  const int gw = (blockIdx.x * blockDim.x + threadIdx.x) >> 6;
  const int lane = threadIdx.x & 63;
  if (gw >= BATCH * 10) return;
  const int m = gw / 10, cls = gw % 10;
  float s = 0.f;
  for (int k = lane; k < HID; k += 64)
    s += (float)h[(size_t)m * HID + k] * fw[(size_t)cls * HID + k];
#pragma unroll
  for (int off = 32; off; off >>= 1) s += __shfl_down(s, off);
  if (lane == 0) out[m * 10 + cls] = s + fb[cls];
}

// ---------------------------------------------------------------------------
extern "C" void kernel_launch(void* const* d_in, const int* in_sizes, int n_in,
                              void* d_out, int out_size, void* d_ws, size_t ws_size,
                              hipStream_t stream)
{
  const float* x      = (const float*)d_in[0];   // [256][64][1024]
  const float* weight = (const float*)d_in[1];   // [2][2][4096][1024]
  const float* bias   = (const float*)d_in[2];   // [2][2][4096]
  const float* fc_w   = (const float*)d_in[3];   // [10][1024]
  const float* fc_b   = (const float*)d_in[4];   // [10]
  float* out = (float*)d_out;                    // [64][10]

  auto align = [](size_t v) { return (v + 255) & ~(size_t)255; };
  const size_t flags_sz = (size_t)NBLK * FLAG_STRIDE * sizeof(unsigned); // 32 KB
  const size_t x16_sz  = (size_t)S_LEN * BATCH * HID * sizeof(h16);      // 32 MB
  const size_t ring_sz = (size_t)2 * BATCH * HID * sizeof(h16);          // 256 KB

  char* p = (char*)d_ws;
  unsigned* flags = (unsigned*)p; p += align(flags_sz);
  unsigned* go    = (unsigned*)p; p += 256;
  h16* x16 = (h16*)p; p += align(x16_sz);
  h16* h0r = (h16*)p; p += align(ring_sz);
  h16* h1r = (h16*)p; p += align(ring_sz);

  hipMemsetAsync(flags, 0, flags_sz, stream);
  hipMemsetAsync(go, 0, 256, stream);
  hipMemsetAsync(h0r, 0, ring_sz, stream);
  hipMemsetAsync(h1r, 0, ring_sz, stream);

  xconv_kernel<<<dim3(2048), 256, 0, stream>>>(x, x16);

  lstm_persistent<<<dim3(NBLK), dim3(256), 0, stream>>>(
      x16, weight, bias, h0r, h1r, flags, go);

  // final h of top layer: t = 255 -> ring slot 1
  fc_kernel<<<dim3((BATCH * 10 * 64) / 256), 256, 0, stream>>>(
      h1r + (size_t)BATCH * HID, fc_w, fc_b, out);
}

// Round 7
// 4631.171 us; speedup vs baseline: 1.2187x; 1.1663x over previous
//
#include <hip/hip_runtime.h>
#include <cstdint>
#include <cstddef>

#define S_LEN 256
#define BATCH 64
#define HID   1024
#define GATES 4096
#define NBLK  256
#define FLAG_STRIDE 32   // 32 uints = 128 B: one cache line per block's flag

typedef _Float16 h16;
typedef _Float16 h16x8 __attribute__((ext_vector_type(8)));
typedef _Float16 h16x4 __attribute__((ext_vector_type(4)));
typedef float    f32x4 __attribute__((ext_vector_type(4)));

// ---------------------------------------------------------------------------
// x fp32 -> fp16 (one pass)
// ---------------------------------------------------------------------------
__global__ __launch_bounds__(256)
void xconv_kernel(const float* __restrict__ x, h16* __restrict__ x16)
{
  const int n4 = S_LEN * BATCH * HID / 4;
  const int stride = gridDim.x * 256;
  for (int i = blockIdx.x * 256 + threadIdx.x; i < n4; i += stride) {
    f32x4 v = ((const f32x4*)x)[i];
    h16x4 o;
    o[0] = (h16)v[0]; o[1] = (h16)v[1]; o[2] = (h16)v[2]; o[3] = (h16)v[3];
    ((h16x4*)x16)[i] = o;
  }
}

// ---------------------------------------------------------------------------
// Flat one-hop grid barrier (R4 rel/acq semantics, no block-0 relay):
// each block release-stores its own padded flag; threads 0..NBLK-1 of EVERY
// block poll one flag each; one acquire load invalidates L1/L2 afterwards.
// Monotone counters; flags zeroed per kernel_launch.
// ---------------------------------------------------------------------------
__device__ __forceinline__ void grid_barrier(unsigned* flags, int g, int wg)
{
  __syncthreads();                      // vmcnt drained: h-stores issued
  const unsigned tgt = (unsigned)(g + 1);
  if (threadIdx.x == 0)
    __hip_atomic_store(&flags[wg * FLAG_STRIDE], tgt,
                       __ATOMIC_RELEASE, __HIP_MEMORY_SCOPE_AGENT);
  if (threadIdx.x < NBLK) {
    while (__hip_atomic_load(&flags[threadIdx.x * FLAG_STRIDE],
                             __ATOMIC_RELAXED, __HIP_MEMORY_SCOPE_AGENT) < tgt) {}
  }
  if (threadIdx.x == 0)
    (void)__hip_atomic_load(&flags[0], __ATOMIC_ACQUIRE, __HIP_MEMORY_SCOPE_AGENT);
  __syncthreads();
}

// ---------------------------------------------------------------------------
// Persistent 2-layer pipelined LSTM. 256 WGs x 512 thr (8 waves, 2/SIMD).
// WG wg: layer = wg>>7, owns hidden cols j0..j0+7 (32 gate-cols = 2 n-tiles).
// Wave w owns K-slice [w*256,(w+1)*256): waves 0-3 input part (x or h0),
// waves 4-7 hidden part (h_prev). Weights fp16 in 128KB LDS (loaded once),
// layout [wave][n2][s][lane][8]. Step g: layer0 does t=g, layer1 does t=g-1.
// 8-way cross-wave K-reduce via 16KB XOR-swizzled LDS, 4 m-rounds of 16 rows;
// gates+c+h fused (c in regs of threads 0-127).
// ---------------------------------------------------------------------------
__global__ __launch_bounds__(512, 1)
void lstm_persistent(const h16* __restrict__ x16,
                     const float* __restrict__ weight,
                     const float* __restrict__ bias,
                     h16* __restrict__ h0r,
                     h16* __restrict__ h1r,
                     unsigned* __restrict__ flags)
{
  __shared__ h16   wlds[65536];        // 128 KB: [8 w][2 n2][8 s][64 lane][8]
  __shared__ float plds[8][16][32];    // 16 KB

  const int wg    = blockIdx.x;
  const int layer = wg >> 7;
  const int j0    = (wg & 127) * 8;
  const int tid   = threadIdx.x;
  const int wave  = tid >> 6, lane = tid & 63;
  const int l15   = lane & 15, l16 = lane >> 4;

  // ---- one-time: pack this WG's weight slice fp32->fp16 into LDS ----
  {
    const float* wsrc = weight + (size_t)layer * 2 * GATES * HID;
    for (int c = tid; c < 8192; c += 512) {   // c = ((w*2+n2)*8+s)*64 + ln
      const int ln = c & 63, s = (c >> 6) & 7, n2 = (c >> 9) & 1, w = c >> 10;
      const int lc  = n2 * 16 + (ln & 15);              // local col 0..31
      const int col = (lc >> 3) * HID + j0 + (lc & 7);  // global gate col
      const int k   = w * 256 + s * 32 + (ln >> 4) * 8; // global K
      const float* p = wsrc + (k < HID ? (size_t)0 : (size_t)GATES * HID)
                            + (size_t)col * HID + (k & (HID - 1));
      h16x8 v;
#pragma unroll
      for (int e = 0; e < 8; ++e) v[e] = (h16)p[e];
      *(h16x8*)&wlds[(size_t)c * 8] = v;
    }
  }
  // combined bias for this thread's j (threads 0-127 use it)
  float bc[4];
  {
    const int j = tid & 7;
#pragma unroll
    for (int gg = 0; gg < 4; ++gg) {
      const int col = gg * HID + j0 + j;
      bc[gg] = bias[(size_t)layer * 2 * GATES + col] +
               bias[(size_t)layer * 2 * GATES + GATES + col];
    }
  }
  float creg[4] = {0.f, 0.f, 0.f, 0.f};
  __syncthreads();

  for (int g = 0; g <= S_LEN; ++g) {
    const bool active = (layer == 0) ? (g < S_LEN) : (g >= 1);
    if (active) {
      const h16 *Alo, *Ahi;
      h16* Hout;
      if (layer == 0) {
        Alo  = x16 + (size_t)g * (BATCH * HID);
        Ahi  = h0r + (size_t)((g + 1) & 1) * (BATCH * HID);
        Hout = h0r + (size_t)(g & 1) * (BATCH * HID);
      } else {
        Alo  = h0r + (size_t)((g - 1) & 1) * (BATCH * HID);
        Ahi  = h1r + (size_t)(g & 1) * (BATCH * HID);
        Hout = h1r + (size_t)((g - 1) & 1) * (BATCH * HID);
      }
      const h16* Asrc = (wave < 4) ? Alo : Ahi;
      const int kb = (wave & 3) * 256;

      const h16* arow[4];
#pragma unroll
      for (int i = 0; i < 4; ++i)
        arow[i] = Asrc + (size_t)(i * 16 + l15) * HID + kb + l16 * 8;
      const h16* bb = wlds + (size_t)wave * 8192 + lane * 8;  // n2 stride 4096

      f32x4 acc[4][2];
#pragma unroll
      for (int i = 0; i < 4; ++i)
#pragma unroll
        for (int n2 = 0; n2 < 2; ++n2) acc[i][n2] = (f32x4)0.f;

#pragma unroll
      for (int s = 0; s < 8; ++s) {
        const h16x8 b0 = *(const h16x8*)(bb + s * 512);
        const h16x8 b1 = *(const h16x8*)(bb + 4096 + s * 512);
#pragma unroll
        for (int i = 0; i < 4; ++i) {
          const h16x8 a = *(const h16x8*)(arow[i] + s * 32);
          acc[i][0] = __builtin_amdgcn_mfma_f32_16x16x32_f16(a, b0, acc[i][0], 0, 0, 0);
          acc[i][1] = __builtin_amdgcn_mfma_f32_16x16x32_f16(a, b1, acc[i][1], 0, 0, 0);
        }
      }

      // ---- 8-way cross-wave reduce + activations, 4 m-rounds of 16 rows ----
#pragma unroll
      for (int i = 0; i < 4; ++i) {
#pragma unroll
        for (int n2 = 0; n2 < 2; ++n2)
#pragma unroll
          for (int q = 0; q < 4; ++q) {
            const int r = l16 * 4 + q;                        // 0..15
            const int colS = (n2 * 16 + l15) ^ ((r & 7) << 2);
            plds[wave][r][colS] = acc[i][n2][q];
          }
        __syncthreads();
        if (tid < 128) {
          const int r = tid >> 3, j = tid & 7;
          float gv[4];
#pragma unroll
          for (int gg = 0; gg < 4; ++gg) {
            const int colS = (gg * 8 + j) ^ ((r & 7) << 2);
            float s = bc[gg];
#pragma unroll
            for (int w = 0; w < 8; ++w) s += plds[w][r][colS];
            gv[gg] = s;
          }
          const float ig = 1.f / (1.f + __expf(-gv[0]));
          const float fg = 1.f / (1.f + __expf(-gv[1]));
          const float gt = 1.f - 2.f / (__expf(2.f * gv[2]) + 1.f);
          const float og = 1.f / (1.f + __expf(-gv[3]));
          const float cn = fg * creg[i] + ig * gt;
          creg[i] = cn;
          const float th = 1.f - 2.f / (__expf(2.f * cn) + 1.f);
          Hout[(size_t)(i * 16 + r) * HID + j0 + j] = (h16)(og * th);
        }
        __syncthreads();
      }
    }
    grid_barrier(flags, g, wg);
  }
}

// ---------------------------------------------------------------------------
// out[m][cls] = h[m] . fc_w[cls] + fc_b[cls]. One wave per output.
// ---------------------------------------------------------------------------
__global__ __launch_bounds__(256)
void fc_kernel(const h16* __restrict__ h,
               const float* __restrict__ fw,
               const float* __restrict__ fb,
               float* __restrict__ out)
{
  const int gw = (blockIdx.x * blockDim.x + threadIdx.x) >> 6;
  const int lane = threadIdx.x & 63;
  if (gw >= BATCH * 10) return;
  const int m = gw / 10, cls = gw % 10;
  float s = 0.f;
  for (int k = lane; k < HID; k += 64)
    s += (float)h[(size_t)m * HID + k] * fw[(size_t)cls * HID + k];
#pragma unroll
  for (int off = 32; off; off >>= 1) s += __shfl_down(s, off);
  if (lane == 0) out[m * 10 + cls] = s + fb[cls];
}

// ---------------------------------------------------------------------------
extern "C" void kernel_launch(void* const* d_in, const int* in_sizes, int n_in,
                              void* d_out, int out_size, void* d_ws, size_t ws_size,
                              hipStream_t stream)
{
  const float* x      = (const float*)d_in[0];   // [256][64][1024]
  const float* weight = (const float*)d_in[1];   // [2][2][4096][1024]
  const float* bias   = (const float*)d_in[2];   // [2][2][4096]
  const float* fc_w   = (const float*)d_in[3];   // [10][1024]
  const float* fc_b   = (const float*)d_in[4];   // [10]
  float* out = (float*)d_out;                    // [64][10]

  auto align = [](size_t v) { return (v + 255) & ~(size_t)255; };
  const size_t flags_sz = (size_t)NBLK * FLAG_STRIDE * sizeof(unsigned); // 32 KB
  const size_t x16_sz  = (size_t)S_LEN * BATCH * HID * sizeof(h16);      // 32 MB
  const size_t ring_sz = (size_t)2 * BATCH * HID * sizeof(h16);          // 256 KB

  char* p = (char*)d_ws;
  unsigned* flags = (unsigned*)p; p += align(flags_sz);
  h16* x16 = (h16*)p; p += align(x16_sz);
  h16* h0r = (h16*)p; p += align(ring_sz);
  h16* h1r = (h16*)p; p += align(ring_sz);

  hipMemsetAsync(flags, 0, flags_sz, stream);
  hipMemsetAsync(h0r, 0, ring_sz, stream);
  hipMemsetAsync(h1r, 0, ring_sz, stream);

  xconv_kernel<<<dim3(2048), 256, 0, stream>>>(x, x16);

  lstm_persistent<<<dim3(NBLK), dim3(512), 0, stream>>>(
      x16, weight, bias, h0r, h1r, flags);

  // final h of top layer: t = 255 -> ring slot 1
  fc_kernel<<<dim3((BATCH * 10 * 64) / 256), 256, 0, stream>>>(
      h1r + (size_t)BATCH * HID, fc_w, fc_b, out);
}

// Round 8
// 3170.956 us; speedup vs baseline: 1.7799x; 1.4605x over previous
//
#include <hip/hip_runtime.h>
#include <cstdint>
#include <cstddef>

#define S_LEN 256
#define BATCH 64
#define HID   1024
#define GATES 4096
#define NBLK  256
#define FLAG_STRIDE 32   // 32 uints = 128 B: one cache line per block's flag

typedef _Float16 h16;
typedef _Float16 h16x8 __attribute__((ext_vector_type(8)));
typedef _Float16 h16x4 __attribute__((ext_vector_type(4)));
typedef float    f32x4 __attribute__((ext_vector_type(4)));

// ---------------------------------------------------------------------------
// x fp32 -> fp16 (one pass)
// ---------------------------------------------------------------------------
__global__ __launch_bounds__(256)
void xconv_kernel(const float* __restrict__ x, h16* __restrict__ x16)
{
  const int n4 = S_LEN * BATCH * HID / 4;
  const int stride = gridDim.x * 256;
  for (int i = blockIdx.x * 256 + threadIdx.x; i < n4; i += stride) {
    f32x4 v = ((const f32x4*)x)[i];
    h16x4 o;
    o[0] = (h16)v[0]; o[1] = (h16)v[1]; o[2] = (h16)v[2]; o[3] = (h16)v[3];
    ((h16x4*)x16)[i] = o;
  }
}

// ---------------------------------------------------------------------------
// Flat one-hop grid barrier with NO wbl2 (no release anywhere):
//  - h-ring payload is sc1 write-through (agent relaxed stores) -> already at
//    L3 once vmcnt drains; flag store is relaxed too (no cache maintenance).
//  - threads 0..NBLK-1 of every block poll one flag each (relaxed, sc1->L3).
//  - after ALL flags observed, ONE acquire load per block emits buffer_inv
//    (L1+L2 invalidate) so the next step's plain cached ring/x loads refill
//    fresh from L3. This is the only cache-maintenance op per block per step.
// Monotone counters; flags zeroed per kernel_launch.
// ---------------------------------------------------------------------------
__device__ __forceinline__ void grid_barrier(unsigned* flags, int g, int wg)
{
  __syncthreads();                      // vmcnt drained: sc1 h-stores at L3
  const unsigned tgt = (unsigned)(g + 1);
  if (threadIdx.x == 0)
    __hip_atomic_store(&flags[wg * FLAG_STRIDE], tgt,
                       __ATOMIC_RELAXED, __HIP_MEMORY_SCOPE_AGENT);
  if (threadIdx.x < NBLK) {
    while (__hip_atomic_load(&flags[threadIdx.x * FLAG_STRIDE],
                             __ATOMIC_RELAXED, __HIP_MEMORY_SCOPE_AGENT) < tgt) {}
  }
  __syncthreads();                      // all 256 flags observed by this block
  if (threadIdx.x == 0)
    (void)__hip_atomic_load(&flags[0], __ATOMIC_ACQUIRE,
                            __HIP_MEMORY_SCOPE_AGENT);   // buffer_inv only
  __syncthreads();
}

// ---------------------------------------------------------------------------
// Persistent 2-layer pipelined LSTM. 256 WGs x 512 thr (8 waves, 2/SIMD).
// WG wg: layer = wg>>7, owns hidden cols j0..j0+7 (32 gate-cols = 2 n-tiles).
// Wave w owns K-slice [w*256,(w+1)*256): waves 0-3 input part (x or h0),
// waves 4-7 hidden part (h_prev). Weights fp16 in 128KB LDS (loaded once),
// layout [wave][n2][s][lane][8]. Step g: layer0 does t=g, layer1 does t=g-1.
// Ring data: plain cached loads (per-XCD L2 shares the fill; freshness by the
// barrier's buffer_inv); h stores are sc1 write-through (never dirty in L2).
// 8-way cross-wave K-reduce via 16KB XOR-swizzled LDS, 4 m-rounds of 16 rows.
// ---------------------------------------------------------------------------
__global__ __launch_bounds__(512, 1)
void lstm_persistent(const h16* __restrict__ x16,
                     const float* __restrict__ weight,
                     const float* __restrict__ bias,
                     h16* __restrict__ h0r,
                     h16* __restrict__ h1r,
                     unsigned* __restrict__ flags)
{
  __shared__ h16   wlds[65536];        // 128 KB: [8 w][2 n2][8 s][64 lane][8]
  __shared__ float plds[8][16][32];    // 16 KB

  const int wg    = blockIdx.x;
  const int layer = wg >> 7;
  const int j0    = (wg & 127) * 8;
  const int tid   = threadIdx.x;
  const int wave  = tid >> 6, lane = tid & 63;
  const int l15   = lane & 15, l16 = lane >> 4;

  // ---- one-time: pack this WG's weight slice fp32->fp16 into LDS ----
  {
    const float* wsrc = weight + (size_t)layer * 2 * GATES * HID;
    for (int c = tid; c < 8192; c += 512) {   // c = ((w*2+n2)*8+s)*64 + ln
      const int ln = c & 63, s = (c >> 6) & 7, n2 = (c >> 9) & 1, w = c >> 10;
      const int lc  = n2 * 16 + (ln & 15);              // local col 0..31
      const int col = (lc >> 3) * HID + j0 + (lc & 7);  // global gate col
      const int k   = w * 256 + s * 32 + (ln >> 4) * 8; // global K
      const float* p = wsrc + (k < HID ? (size_t)0 : (size_t)GATES * HID)
                            + (size_t)col * HID + (k & (HID - 1));
      h16x8 v;
#pragma unroll
      for (int e = 0; e < 8; ++e) v[e] = (h16)p[e];
      *(h16x8*)&wlds[(size_t)c * 8] = v;
    }
  }
  // combined bias for this thread's j (threads 0-127 use it)
  float bc[4];
  {
    const int j = tid & 7;
#pragma unroll
    for (int gg = 0; gg < 4; ++gg) {
      const int col = gg * HID + j0 + j;
      bc[gg] = bias[(size_t)layer * 2 * GATES + col] +
               bias[(size_t)layer * 2 * GATES + GATES + col];
    }
  }
  float creg[4] = {0.f, 0.f, 0.f, 0.f};
  __syncthreads();

  for (int g = 0; g <= S_LEN; ++g) {
    const bool active = (layer == 0) ? (g < S_LEN) : (g >= 1);
    if (active) {
      const h16 *Alo, *Ahi;
      h16* Hout;
      if (layer == 0) {
        Alo  = x16 + (size_t)g * (BATCH * HID);
        Ahi  = h0r + (size_t)((g + 1) & 1) * (BATCH * HID);
        Hout = h0r + (size_t)(g & 1) * (BATCH * HID);
      } else {
        Alo  = h0r + (size_t)((g - 1) & 1) * (BATCH * HID);
        Ahi  = h1r + (size_t)(g & 1) * (BATCH * HID);
        Hout = h1r + (size_t)((g - 1) & 1) * (BATCH * HID);
      }
      const h16* Asrc = (wave < 4) ? Alo : Ahi;
      const int kb = (wave & 3) * 256;

      const h16* arow[4];
#pragma unroll
      for (int i = 0; i < 4; ++i)
        arow[i] = Asrc + (size_t)(i * 16 + l15) * HID + kb + l16 * 8;
      const h16* bb = wlds + (size_t)wave * 8192 + lane * 8;  // n2 stride 4096

      f32x4 acc[4][2];
#pragma unroll
      for (int i = 0; i < 4; ++i)
#pragma unroll
        for (int n2 = 0; n2 < 2; ++n2) acc[i][n2] = (f32x4)0.f;

#pragma unroll
      for (int s = 0; s < 8; ++s) {
        const h16x8 b0 = *(const h16x8*)(bb + s * 512);
        const h16x8 b1 = *(const h16x8*)(bb + 4096 + s * 512);
#pragma unroll
        for (int i = 0; i < 4; ++i) {
          const h16x8 a = *(const h16x8*)(arow[i] + s * 32);
          acc[i][0] = __builtin_amdgcn_mfma_f32_16x16x32_f16(a, b0, acc[i][0], 0, 0, 0);
          acc[i][1] = __builtin_amdgcn_mfma_f32_16x16x32_f16(a, b1, acc[i][1], 0, 0, 0);
        }
      }

      // ---- 8-way cross-wave reduce + activations, 4 m-rounds of 16 rows ----
#pragma unroll
      for (int i = 0; i < 4; ++i) {
#pragma unroll
        for (int n2 = 0; n2 < 2; ++n2)
#pragma unroll
          for (int q = 0; q < 4; ++q) {
            const int r = l16 * 4 + q;                        // 0..15
            const int colS = (n2 * 16 + l15) ^ ((r & 7) << 2);
            plds[wave][r][colS] = acc[i][n2][q];
          }
        __syncthreads();
        if (tid < 128) {
          const int r = tid >> 3, j = tid & 7;
          float gv[4];
#pragma unroll
          for (int gg = 0; gg < 4; ++gg) {
            const int colS = (gg * 8 + j) ^ ((r & 7) << 2);
            float s = bc[gg];
#pragma unroll
            for (int w = 0; w < 8; ++w) s += plds[w][r][colS];
            gv[gg] = s;
          }
          const float ig = 1.f / (1.f + __expf(-gv[0]));
          const float fg = 1.f / (1.f + __expf(-gv[1]));
          const float gt = 1.f - 2.f / (__expf(2.f * gv[2]) + 1.f);
          const float og = 1.f / (1.f + __expf(-gv[3]));
          const float cn = fg * creg[i] + ig * gt;
          creg[i] = cn;
          const float th = 1.f - 2.f / (__expf(2.f * cn) + 1.f);
          union { h16 f; unsigned short u; } hb;
          hb.f = (h16)(og * th);
          __hip_atomic_store(
              (unsigned short*)&Hout[(size_t)(i * 16 + r) * HID + j0 + j],
              hb.u, __ATOMIC_RELAXED, __HIP_MEMORY_SCOPE_AGENT);
        }
        __syncthreads();
      }
    }
    grid_barrier(flags, g, wg);
  }
}

// ---------------------------------------------------------------------------
// out[m][cls] = h[m] . fc_w[cls] + fc_b[cls]. One wave per output.
// ---------------------------------------------------------------------------
__global__ __launch_bounds__(256)
void fc_kernel(const h16* __restrict__ h,
               const float* __restrict__ fw,
               const float* __restrict__ fb,
               float* __restrict__ out)
{
  const int gw = (blockIdx.x * blockDim.x + threadIdx.x) >> 6;
  const int lane = threadIdx.x & 63;
  if (gw >= BATCH * 10) return;
  const int m = gw / 10, cls = gw % 10;
  float s = 0.f;
  for (int k = lane; k < HID; k += 64)
    s += (float)h[(size_t)m * HID + k] * fw[(size_t)cls * HID + k];
#pragma unroll
  for (int off = 32; off; off >>= 1) s += __shfl_down(s, off);
  if (lane == 0) out[m * 10 + cls] = s + fb[cls];
}

// ---------------------------------------------------------------------------
extern "C" void kernel_launch(void* const* d_in, const int* in_sizes, int n_in,
                              void* d_out, int out_size, void* d_ws, size_t ws_size,
                              hipStream_t stream)
{
  const float* x      = (const float*)d_in[0];   // [256][64][1024]
  const float* weight = (const float*)d_in[1];   // [2][2][4096][1024]
  const float* bias   = (const float*)d_in[2];   // [2][2][4096]
  const float* fc_w   = (const float*)d_in[3];   // [10][1024]
  const float* fc_b   = (const float*)d_in[4];   // [10]
  float* out = (float*)d_out;                    // [64][10]

  auto align = [](size_t v) { return (v + 255) & ~(size_t)255; };
  const size_t flags_sz = (size_t)NBLK * FLAG_STRIDE * sizeof(unsigned); // 32 KB
  const size_t x16_sz  = (size_t)S_LEN * BATCH * HID * sizeof(h16);      // 32 MB
  const size_t ring_sz = (size_t)2 * BATCH * HID * sizeof(h16);          // 256 KB

  char* p = (char*)d_ws;
  unsigned* flags = (unsigned*)p; p += align(flags_sz);
  h16* x16 = (h16*)p; p += align(x16_sz);
  h16* h0r = (h16*)p; p += align(ring_sz);
  h16* h1r = (h16*)p; p += align(ring_sz);

  hipMemsetAsync(flags, 0, flags_sz, stream);
  hipMemsetAsync(h0r, 0, ring_sz, stream);
  hipMemsetAsync(h1r, 0, ring_sz, stream);

  xconv_kernel<<<dim3(2048), 256, 0, stream>>>(x, x16);

  lstm_persistent<<<dim3(NBLK), dim3(512), 0, stream>>>(
      x16, weight, bias, h0r, h1r, flags);

  // final h of top layer: t = 255 -> ring slot 1
  fc_kernel<<<dim3((BATCH * 10 * 64) / 256), 256, 0, stream>>>(
      h1r + (size_t)BATCH * HID, fc_w, fc_b, out);
}